// Round 1
// baseline (127.944 us; speedup 1.0000x reference)
//
#include <hip/hip_runtime.h>
#include <hip/hip_bf16.h>
#include <stdint.h>

typedef uint32_t u32;
typedef uint64_t u64;

// Problem constants (from reference)
constexpr int BATCH = 8;
constexpr int L = 32768;
constexpr int C = 128;          // channels
constexpr int N = BATCH * L;    // 262144 points
constexpr int NBUCKET = 1 << 14;  // 16384 buckets on top-14 bits of 30-bit key
// key = (batch<<27)|(x<<18)|(y<<9)|z  (30 bits); bucket = key >> 16

// ---------------- K1: keys + bucket histogram ----------------
__global__ __launch_bounds__(256) void k_keys_hist(const int* __restrict__ coords,
                                                   int* __restrict__ keys,
                                                   u32* __restrict__ hist) {
    int i = blockIdx.x * 256 + threadIdx.x;
    int batch = i >> 15;  // i / L
    int x = coords[3 * i + 0];
    int y = coords[3 * i + 1];
    int z = coords[3 * i + 2];
    int key = (batch << 27) | (x << 18) | (y << 9) | z;
    keys[i] = key;
    atomicAdd(&hist[(u32)key >> 16], 1u);
}

// ---------------- K2: exclusive scan of 16384 bucket counts (1 block) ----------------
__global__ __launch_bounds__(1024) void k_scan_buckets(const u32* __restrict__ hist,
                                                       u32* __restrict__ bstart) {
    __shared__ u32 s[1024];
    int t = threadIdx.x;
    u32 loc[16];
    u32 sum = 0;
    for (int k = 0; k < 16; ++k) { loc[k] = sum; sum += hist[t * 16 + k]; }
    s[t] = sum;
    __syncthreads();
    for (int off = 1; off < 1024; off <<= 1) {
        u32 v = (t >= off) ? s[t - off] : 0u;
        __syncthreads();
        s[t] += v;
        __syncthreads();
    }
    u32 base = (t == 0) ? 0u : s[t - 1];
    for (int k = 0; k < 16; ++k) bstart[t * 16 + k] = base + loc[k];
    if (t == 1023) bstart[NBUCKET] = s[1023];
}

// ---------------- K3: scatter packed (key,idx) into bucket-contiguous order ----------------
__global__ __launch_bounds__(256) void k_scatter(const int* __restrict__ keys,
                                                 const u32* __restrict__ bstart,
                                                 u32* __restrict__ cursor,
                                                 u64* __restrict__ bucketed) {
    int i = blockIdx.x * 256 + threadIdx.x;
    u32 key = (u32)keys[i];
    u32 b = key >> 16;
    u32 pos = bstart[b] + atomicAdd(&cursor[b], 1u);
    bucketed[pos] = ((u64)key << 32) | (u32)i;
}

// ---------------- K4: per-bucket exact sort by rank-counting (values distinct) ----------------
__global__ __launch_bounds__(64) void k_sort_buckets(const u32* __restrict__ bstart,
                                                     const u64* __restrict__ bucketed,
                                                     u64* __restrict__ sorted) {
    int b = blockIdx.x;
    u32 s0 = bstart[b];
    u32 e = bstart[b + 1];
    int m = (int)(e - s0);
    if (m <= 0) return;
    __shared__ u64 lds[1024];
    int lane = threadIdx.x;
    if (m <= 1024) {
        for (int k = lane; k < m; k += 64) lds[k] = bucketed[s0 + k];
        __syncthreads();
        for (int j = lane; j < m; j += 64) {
            u64 v = lds[j];
            int cnt = 0;
            for (int k = 0; k < m; ++k) cnt += (lds[k] < v) ? 1 : 0;
            sorted[s0 + cnt] = v;
        }
    } else {  // safety fallback (won't trigger for uniform random input)
        for (int j = lane; j < m; j += 64) {
            u64 v = bucketed[s0 + j];
            int cnt = 0;
            for (int k = 0; k < m; ++k) cnt += (bucketed[s0 + k] < v) ? 1 : 0;
            sorted[s0 + cnt] = v;
        }
    }
}

// ---------------- K5: per-block sums of head flags ----------------
__global__ __launch_bounds__(1024) void k_head_sums(const u64* __restrict__ sorted,
                                                    u32* __restrict__ blockSums) {
    int i = blockIdx.x * 1024 + threadIdx.x;
    int head = (i == 0) || ((u32)(sorted[i] >> 32) != (u32)(sorted[i - 1] >> 32));
    unsigned long long bal = __ballot(head);
    __shared__ u32 wsum[16];
    int wave = threadIdx.x >> 6;
    int lane = threadIdx.x & 63;
    if (lane == 0) wsum[wave] = (u32)__popcll(bal);
    __syncthreads();
    if (threadIdx.x == 0) {
        u32 s = 0;
        for (int w = 0; w < 16; ++w) s += wsum[w];
        blockSums[blockIdx.x] = s;
    }
}

// ---------------- K6: scan 256 block sums (1 block) ----------------
__global__ __launch_bounds__(256) void k_scan_block_sums(const u32* __restrict__ blockSums,
                                                         u32* __restrict__ blockOffs,
                                                         u32* __restrict__ nUnique) {
    __shared__ u32 s[256];
    int t = threadIdx.x;
    s[t] = blockSums[t];
    __syncthreads();
    for (int off = 1; off < 256; off <<= 1) {
        u32 v = (t >= off) ? s[t - off] : 0u;
        __syncthreads();
        s[t] += v;
        __syncthreads();
    }
    blockOffs[t] = (t == 0) ? 0u : s[t - 1];
    if (t == 255) *nUnique = s[255];
}

// ---------------- K7: write rank (number of heads strictly before a head position) ----------------
__global__ __launch_bounds__(1024) void k_ranks(const u64* __restrict__ sorted,
                                                const u32* __restrict__ blockOffs,
                                                int* __restrict__ rank) {
    int i = blockIdx.x * 1024 + threadIdx.x;
    int head = (i == 0) || ((u32)(sorted[i] >> 32) != (u32)(sorted[i - 1] >> 32));
    unsigned long long bal = __ballot(head);
    int wave = threadIdx.x >> 6;
    int lane = threadIdx.x & 63;
    u32 lanePrefix = (u32)__popcll(bal & ((1ULL << lane) - 1ULL));
    __shared__ u32 wsum[16];
    __shared__ u32 woff[16];
    if (lane == 63) wsum[wave] = (u32)__popcll(bal);
    __syncthreads();
    if (threadIdx.x == 0) {
        u32 s = 0;
        for (int w = 0; w < 16; ++w) { woff[w] = s; s += wsum[w]; }
    }
    __syncthreads();
    // For head positions this is exactly (#heads before i) == unique-rank of this segment.
    rank[i] = (int)(blockOffs[blockIdx.x] + woff[wave] + lanePrefix);
}

// ---------------- K8: gather-sum segments into output rows; zero padded rows ----------------
__global__ __launch_bounds__(64) void k_gather(const u64* __restrict__ sorted,
                                               const int* __restrict__ rank,
                                               const u32* __restrict__ nUnique,
                                               const float* __restrict__ feats,
                                               float* __restrict__ out) {
    int i = blockIdx.x;
    int lane = threadIdx.x;  // 0..63, each handles a float2 (C=128)
    u64 vi = sorted[i];
    u32 k0 = (u32)(vi >> 32);
    bool head = (i == 0) || (k0 != (u32)(sorted[i - 1] >> 32));
    if (head) {
        float2 acc = make_float2(0.f, 0.f);
        int j = i;
        do {
            u32 idx = (u32)sorted[j];  // low 32 bits = original point index
            const float2* f = (const float2*)(feats + (size_t)idx * C);
            float2 v = f[lane];
            acc.x += v.x;
            acc.y += v.y;
            ++j;
        } while (j < N && (u32)(sorted[j] >> 32) == k0);
        int r = rank[i];
        ((float2*)(out + (size_t)r * C))[lane] = acc;
    }
    u32 nu = *nUnique;
    if ((u32)i >= nu) {
        ((float2*)(out + (size_t)i * C))[lane] = make_float2(0.f, 0.f);
    }
}

extern "C" void kernel_launch(void* const* d_in, const int* in_sizes, int n_in,
                              void* d_out, int out_size, void* d_ws, size_t ws_size,
                              hipStream_t stream) {
    const int* coords = (const int*)d_in[0];
    const float* feats = (const float*)d_in[1];
    float* out = (float*)d_out;

    char* w = (char*)d_ws;
    u64* bucketed = (u64*)(w);                      // 2 MiB
    u64* sorted   = (u64*)(w + (size_t)2 * 1024 * 1024);  // 2 MiB
    int* keys     = (int*)(w + (size_t)4 * 1024 * 1024);  // 1 MiB
    int* rank     = (int*)(w + (size_t)5 * 1024 * 1024);  // 1 MiB
    u32* hist     = (u32*)(w + (size_t)6 * 1024 * 1024);  // 64 KiB
    u32* cursor   = hist + NBUCKET;                        // 64 KiB
    u32* bstart   = cursor + NBUCKET;                      // 16385 * 4
    u32* blockSums = bstart + NBUCKET + 1;                 // 256 * 4
    u32* blockOffs = blockSums + 256;                      // 256 * 4
    u32* nUniq     = blockOffs + 256;                      // 4

    // zero hist + cursor (contiguous 128 KiB)
    hipMemsetAsync(hist, 0, (size_t)2 * NBUCKET * sizeof(u32), stream);

    k_keys_hist<<<N / 256, 256, 0, stream>>>(coords, keys, hist);
    k_scan_buckets<<<1, 1024, 0, stream>>>(hist, bstart);
    k_scatter<<<N / 256, 256, 0, stream>>>(keys, bstart, cursor, bucketed);
    k_sort_buckets<<<NBUCKET, 64, 0, stream>>>(bstart, bucketed, sorted);
    k_head_sums<<<N / 1024, 1024, 0, stream>>>(sorted, blockSums);
    k_scan_block_sums<<<1, 256, 0, stream>>>(blockSums, blockOffs, nUniq);
    k_ranks<<<N / 1024, 1024, 0, stream>>>(sorted, blockOffs, rank);
    k_gather<<<N, 64, 0, stream>>>(sorted, rank, nUniq, feats, out);
}